// Round 3
// baseline (189.340 us; speedup 1.0000x reference)
//
#include <hip/hip_runtime.h>
#include <hip/hip_bf16.h>

typedef __bf16 bf16_8 __attribute__((ext_vector_type(8)));
typedef float f32x4 __attribute__((ext_vector_type(4)));

#define MFMA16(A, B, C) __builtin_amdgcn_mfma_f32_16x16x32_bf16(A, B, C, 0, 0, 0)

#define BATCH 8
#define NPOS 4096            // 64*64 spatial
#define CIN 256
#define CMID 64
#define OC 256
#define NROWS (BATCH * NPOS) // 32768

// ---------------------------------------------------------------------------
// proj_kernel: one of {k, q, v} = x @ W  (M=32768, K=256, N=64), computed
// SPLIT-PRECISION: x = xh+xl, W = wh+wl (bf16 pairs), acc = xh*wh + xh*wl
// + xl*wh (lo*lo dropped ~2^-18 rel). Result is fp32-accurate to ~1e-4.
// grid (512, 3), block 256. m=0 -> k hi/lo; m=1 -> q hi/lo; m=2 -> vT bf16
// ---------------------------------------------------------------------------
__global__ __launch_bounds__(256) void proj_kernel(
    const float* __restrict__ x,
    const float* __restrict__ Wk, const float* __restrict__ Wq,
    const float* __restrict__ Wv,
    __bf16* __restrict__ k_hi, __bf16* __restrict__ k_lo,
    __bf16* __restrict__ q_hi, __bf16* __restrict__ q_lo,
    __bf16* __restrict__ vT_ws)
{
    const int m = blockIdx.y;
    const int r0 = blockIdx.x * 64;
    const float* W = (m == 0) ? Wk : (m == 1) ? Wq : Wv;

    // W transposed in LDS, hi/lo split: [col][k], padded rows
    __shared__ __bf16 wth[64][264];
    __shared__ __bf16 wtl[64][264];
    for (int idx = threadIdx.x; idx < 64 * 256; idx += 256) {
        int col = idx & 63, k = idx >> 6;      // coalesced read of W[k][col]
        float f = W[k * 64 + col];
        __bf16 h = (__bf16)f;
        wth[col][k] = h;
        wtl[col][k] = (__bf16)(f - (float)h);
    }
    __syncthreads();

    const int lane = threadIdx.x & 63;
    const int wv = threadIdx.x >> 6;
    const int kbase = ((lane >> 4) & 3) * 8;
    const int arow = r0 + wv * 16 + (lane & 15);

    f32x4 acc[4] = {f32x4{0,0,0,0}, f32x4{0,0,0,0}, f32x4{0,0,0,0}, f32x4{0,0,0,0}};
    const float* xrow = x + (size_t)arow * CIN;

    #pragma unroll
    for (int kk = 0; kk < 8; ++kk) {
        const float4* xp = (const float4*)(xrow + kk * 32 + kbase);
        float4 x0 = xp[0], x1 = xp[1];
        float xs[8] = {x0.x, x0.y, x0.z, x0.w, x1.x, x1.y, x1.z, x1.w};
        bf16_8 ah, al;
        #pragma unroll
        for (int e = 0; e < 8; ++e) {
            __bf16 h = (__bf16)xs[e];
            ah[e] = h;
            al[e] = (__bf16)(xs[e] - (float)h);
        }
        #pragma unroll
        for (int nt = 0; nt < 4; ++nt) {
            bf16_8 bh = *(const bf16_8*)&wth[(lane & 15) + 16 * nt][kk * 32 + kbase];
            bf16_8 bl = *(const bf16_8*)&wtl[(lane & 15) + 16 * nt][kk * 32 + kbase];
            acc[nt] = MFMA16(ah, bh, acc[nt]);
            acc[nt] = MFMA16(ah, bl, acc[nt]);
            acc[nt] = MFMA16(al, bh, acc[nt]);
        }
    }

    // D layout: col = (lane&15)+16nt, row_local = (lane>>4)*4 + r
    const int rrow = r0 + wv * 16 + ((lane >> 4) & 3) * 4;
    if (m < 2) {
        __bf16* dst_hi = (m == 0) ? k_hi : q_hi;
        __bf16* dst_lo = (m == 0) ? k_lo : q_lo;
        #pragma unroll
        for (int nt = 0; nt < 4; ++nt)
            #pragma unroll
            for (int r = 0; r < 4; ++r) {
                float f = acc[nt][r];
                __bf16 h = (__bf16)f;
                size_t idx = (size_t)(rrow + r) * CMID + (lane & 15) + 16 * nt;
                dst_hi[idx] = h;
                dst_lo[idx] = (__bf16)(f - (float)h);
            }
    } else {
        const int b = rrow >> 12;
        const int n = rrow & (NPOS - 1);   // multiple of 4
        #pragma unroll
        for (int nt = 0; nt < 4; ++nt) {
            int cv = (lane & 15) + 16 * nt;
            union { __bf16 h[4]; uint2 u; } pk;
            #pragma unroll
            for (int r = 0; r < 4; ++r) pk.h[r] = (__bf16)acc[nt][r];
            *(uint2*)(vT_ws + ((size_t)b * CMID + cv) * NPOS + n) = pk.u;
        }
    }
}

// ---------------------------------------------------------------------------
// flash_kernel: streaming attention (no max subtraction; unscaled scores)
// scores[i,j] = k[i]·q[j] computed split-precision:
//   s = k_hi·q_hi + k_hi·q_lo + k_lo·q_hi   (lo·lo dropped, ~2^-18 |s|)
// out[i] = sum_j exp(s) v[j] / sum_j exp(s)
// grid (64, 8): blockIdx.x = i-tile (64 rows), blockIdx.y = batch
// ---------------------------------------------------------------------------
__global__ __launch_bounds__(256) void flash_kernel(
    const __bf16* __restrict__ k_hi,   // [32768][64]
    const __bf16* __restrict__ k_lo,
    const __bf16* __restrict__ q_hi,
    const __bf16* __restrict__ q_lo,
    const __bf16* __restrict__ vT_ws,  // [8][64][4096]
    __bf16* __restrict__ attn_ws)      // [32768][64]
{
    const int b = blockIdx.y;
    const int i0 = blockIdx.x * 64;
    const int lane = threadIdx.x & 63;
    const int wv = threadIdx.x >> 6;
    const int kb = ((lane >> 4) & 3) * 8;

    __shared__ __bf16 qth[64][72];       // q hi [j][c]
    __shared__ __bf16 qtl[64][72];       // q lo [j][c]
    __shared__ __bf16 vt[64][72];        // [cv][j]
    __shared__ __bf16 pt[4][16][72];     // per-wave P tile [i][j]

    // K-tile A-fragments held in registers for the whole block lifetime
    bf16_8 a0h, a1h, a0l, a1l;
    {
        size_t off = ((size_t)(b * NPOS + i0 + wv * 16 + (lane & 15))) * CMID + kb;
        a0h = *(const bf16_8*)(k_hi + off);
        a1h = *(const bf16_8*)(k_hi + off + 32);
        a0l = *(const bf16_8*)(k_lo + off);
        a1l = *(const bf16_8*)(k_lo + off + 32);
    }

    f32x4 o[4] = {f32x4{0,0,0,0}, f32x4{0,0,0,0}, f32x4{0,0,0,0}, f32x4{0,0,0,0}};
    float den[4] = {0.f, 0.f, 0.f, 0.f};

    for (int j0 = 0; j0 < NPOS; j0 += 64) {
        // cooperative tile loads: each thread 32B each from q_hi, q_lo, vT
        {
            int r = threadIdx.x >> 2, c0 = (threadIdx.x & 3) * 16;
            size_t qoff = ((size_t)(b * NPOS + j0 + r)) * CMID + c0;
            const uint4* sqh = (const uint4*)(q_hi + qoff);
            uint4 h0 = sqh[0], h1 = sqh[1];
            *(uint4*)&qth[r][c0] = h0;
            *(uint4*)&qth[r][c0 + 8] = h1;
            const uint4* sql = (const uint4*)(q_lo + qoff);
            uint4 l0 = sql[0], l1 = sql[1];
            *(uint4*)&qtl[r][c0] = l0;
            *(uint4*)&qtl[r][c0 + 8] = l1;
            const uint4* sv = (const uint4*)(vT_ws + ((size_t)b * CMID + r) * NPOS + j0 + c0);
            uint4 v0 = sv[0], v1 = sv[1];
            *(uint4*)&vt[r][c0] = v0;
            *(uint4*)&vt[r][c0 + 8] = v1;
        }
        __syncthreads();

        // S fragments: 4 j-subtiles of 16, split-precision (6 MFMA each)
        f32x4 s[4];
        #pragma unroll
        for (int nt = 0; nt < 4; ++nt) {
            bf16_8 b0h = *(const bf16_8*)&qth[(lane & 15) + 16 * nt][kb];
            bf16_8 b1h = *(const bf16_8*)&qth[(lane & 15) + 16 * nt][32 + kb];
            bf16_8 b0l = *(const bf16_8*)&qtl[(lane & 15) + 16 * nt][kb];
            bf16_8 b1l = *(const bf16_8*)&qtl[(lane & 15) + 16 * nt][32 + kb];
            f32x4 z = {0.f, 0.f, 0.f, 0.f};
            z = MFMA16(a0h, b0h, z);
            z = MFMA16(a1h, b1h, z);
            z = MFMA16(a0h, b0l, z);
            z = MFMA16(a1h, b1l, z);
            z = MFMA16(a0l, b0h, z);
            z = MFMA16(a1l, b1h, z);
            s[nt] = z;
        }

        // exp + denominator partials + P into per-wave LDS tile.
        // den accumulates the bf16-ROUNDED p so numerator/denominator are
        // consistent (common-mode rounding cancels in the final divide).
        #pragma unroll
        for (int nt = 0; nt < 4; ++nt) {
            #pragma unroll
            for (int r = 0; r < 4; ++r) {
                float p = __expf(s[nt][r]);
                __bf16 pb = (__bf16)p;
                den[r] += (float)pb;
                pt[wv][((lane >> 4) & 3) * 4 + r][(lane & 15) + 16 * nt] = pb;
            }
        }

        // PV accumulate (same-wave DS write->read; DS ops execute in order per wave)
        #pragma unroll
        for (int kk = 0; kk < 2; ++kk) {
            bf16_8 pa = *(const bf16_8*)&pt[wv][lane & 15][kk * 32 + kb];
            #pragma unroll
            for (int nt = 0; nt < 4; ++nt) {
                bf16_8 vb = *(const bf16_8*)&vt[(lane & 15) + 16 * nt][kk * 32 + kb];
                o[nt] = MFMA16(pa, vb, o[nt]);
            }
        }
        __syncthreads();
    }

    // reduce den across the 16-lane column group (masks 1,2,4,8 keep lane>>4)
    #pragma unroll
    for (int r = 0; r < 4; ++r) {
        float d = den[r];
        d += __shfl_xor(d, 1);
        d += __shfl_xor(d, 2);
        d += __shfl_xor(d, 4);
        d += __shfl_xor(d, 8);
        den[r] = 1.0f / d;
    }

    const int rbase = b * NPOS + i0 + wv * 16 + ((lane >> 4) & 3) * 4;
    #pragma unroll
    for (int nt = 0; nt < 4; ++nt)
        #pragma unroll
        for (int r = 0; r < 4; ++r)
            attn_ws[(size_t)(rbase + r) * CMID + (lane & 15) + 16 * nt] =
                (__bf16)(o[nt][r] * den[r]);
}

// ---------------------------------------------------------------------------
// out_kernel: out = attn @ Wo (K=64) then inference BatchNorm. Coalesced f32.
// grid 2048, block 256 (thread t = output channel), 16 rows per block
// ---------------------------------------------------------------------------
__global__ __launch_bounds__(256) void out_kernel(
    const __bf16* __restrict__ attn_ws, // [32768][64]
    const float* __restrict__ Wo,       // [64][256]
    const float* __restrict__ gamma, const float* __restrict__ beta,
    const float* __restrict__ mmean, const float* __restrict__ mvar,
    float* __restrict__ out)            // [32768][256]
{
    const int r0 = blockIdx.x * 16;
    const int t = threadIdx.x;

    __shared__ float at[16][64];
    for (int idx = t; idx < 16 * 64; idx += 256) {
        int r = idx >> 6, c = idx & 63;
        at[r][c] = (float)attn_ws[(size_t)(r0 + r) * CMID + c];
    }
    __syncthreads();

    float acc[16];
    #pragma unroll
    for (int r = 0; r < 16; ++r) acc[r] = 0.f;

    for (int k = 0; k < 64; ++k) {
        float w = Wo[k * OC + t];
        #pragma unroll
        for (int r = 0; r < 16; ++r) acc[r] += at[r][k] * w;
    }

    const float sc = gamma[t] * rsqrtf(mvar[t] + 1e-3f);
    const float sh = beta[t] - mmean[t] * sc;
    #pragma unroll
    for (int r = 0; r < 16; ++r)
        out[(size_t)(r0 + r) * OC + t] = acc[r] * sc + sh;
}

// ---------------------------------------------------------------------------
extern "C" void kernel_launch(void* const* d_in, const int* in_sizes, int n_in,
                              void* d_out, int out_size, void* d_ws, size_t ws_size,
                              hipStream_t stream) {
    const float* x     = (const float*)d_in[0];
    const float* Wk    = (const float*)d_in[1];
    const float* Wq    = (const float*)d_in[2];
    const float* Wv    = (const float*)d_in[3];
    const float* Wo    = (const float*)d_in[4];
    const float* gamma = (const float*)d_in[5];
    const float* beta  = (const float*)d_in[6];
    const float* mmean = (const float*)d_in[7];
    const float* mvar  = (const float*)d_in[8];
    float* out = (float*)d_out;

    __bf16* k_hi    = (__bf16*)d_ws;                       // 32768*64 each
    __bf16* k_lo    = k_hi + (size_t)NROWS * CMID;
    __bf16* q_hi    = k_lo + (size_t)NROWS * CMID;
    __bf16* q_lo    = q_hi + (size_t)NROWS * CMID;
    __bf16* vT_ws   = q_lo + (size_t)NROWS * CMID;         // 8*64*4096
    __bf16* attn_ws = vT_ws + (size_t)BATCH * CMID * NPOS;
    // total ws: 6 * 32768*64 * 2B = 24 MiB

    proj_kernel<<<dim3(512, 3), 256, 0, stream>>>(x, Wk, Wq, Wv,
                                                  k_hi, k_lo, q_hi, q_lo, vT_ws);
    flash_kernel<<<dim3(64, 8), 256, 0, stream>>>(k_hi, k_lo, q_hi, q_lo,
                                                  vT_ws, attn_ws);
    out_kernel<<<2048, 256, 0, stream>>>(attn_ws, Wo, gamma, beta, mmean, mvar, out);
}

// Round 4
// 127.669 us; speedup vs baseline: 1.4831x; 1.4831x over previous
//
#include <hip/hip_runtime.h>
#include <hip/hip_bf16.h>

typedef __bf16 bf16_8 __attribute__((ext_vector_type(8)));
typedef _Float16 f16x8 __attribute__((ext_vector_type(8)));
typedef float f32x4 __attribute__((ext_vector_type(4)));

#define MFMA_BF(A, B, C) __builtin_amdgcn_mfma_f32_16x16x32_bf16(A, B, C, 0, 0, 0)
#define MFMA_F16(A, B, C) __builtin_amdgcn_mfma_f32_16x16x32_f16(A, B, C, 0, 0, 0)

#define BATCH 8
#define NPOS 4096            // 64*64 spatial
#define CIN 256
#define CMID 64
#define OC 256
#define NROWS (BATCH * NPOS) // 32768
#define NSPLIT 2             // j-range split for flash parallelism

// ---------------------------------------------------------------------------
// proj_kernel (fused): k,q,v = x @ {Wk,Wq,Wv}. x read ONCE into registers
// (bf16 hi/lo pairs), W staged hi/lo in LDS per matrix. Split-precision
// 3-term MFMA gives fp32-accurate results (~1e-4).
// k,q stored fp16 (2^-11 => accurate-enough single-MFMA QK^T downstream);
// v stored bf16 transposed vT[b][cv][n].
// grid 512, block 256.
// ---------------------------------------------------------------------------
__global__ __launch_bounds__(256) void proj_kernel(
    const float* __restrict__ x,
    const float* __restrict__ Wk, const float* __restrict__ Wq,
    const float* __restrict__ Wv,
    _Float16* __restrict__ k_ws, _Float16* __restrict__ q_ws,
    __bf16* __restrict__ vT_ws)
{
    const int r0 = blockIdx.x * 64;

    __shared__ __bf16 wth[64][264];
    __shared__ __bf16 wtl[64][264];

    const int lane = threadIdx.x & 63;
    const int wv = threadIdx.x >> 6;
    const int kbase = ((lane >> 4) & 3) * 8;
    const int arow = r0 + wv * 16 + (lane & 15);
    const float* xrow = x + (size_t)arow * CIN;

    // x tile -> registers, split hi/lo
    bf16_8 ah[8], al[8];
    #pragma unroll
    for (int kk = 0; kk < 8; ++kk) {
        const float4* xp = (const float4*)(xrow + kk * 32 + kbase);
        float4 x0 = xp[0], x1 = xp[1];
        float xs[8] = {x0.x, x0.y, x0.z, x0.w, x1.x, x1.y, x1.z, x1.w};
        #pragma unroll
        for (int e = 0; e < 8; ++e) {
            __bf16 h = (__bf16)xs[e];
            ah[kk][e] = h;
            al[kk][e] = (__bf16)(xs[e] - (float)h);
        }
    }

    const float* Ws[3] = {Wk, Wq, Wv};
    const int rrow = r0 + wv * 16 + ((lane >> 4) & 3) * 4;

    for (int m = 0; m < 3; ++m) {
        __syncthreads();   // previous iteration's LDS reads complete
        for (int idx = threadIdx.x; idx < 64 * 256; idx += 256) {
            int col = idx & 63, k = idx >> 6;
            float f = Ws[m][k * 64 + col];
            __bf16 h = (__bf16)f;
            wth[col][k] = h;
            wtl[col][k] = (__bf16)(f - (float)h);
        }
        __syncthreads();

        f32x4 acc[4] = {f32x4{0,0,0,0}, f32x4{0,0,0,0}, f32x4{0,0,0,0}, f32x4{0,0,0,0}};
        #pragma unroll
        for (int kk = 0; kk < 8; ++kk) {
            #pragma unroll
            for (int nt = 0; nt < 4; ++nt) {
                bf16_8 bh = *(const bf16_8*)&wth[(lane & 15) + 16 * nt][kk * 32 + kbase];
                bf16_8 bl = *(const bf16_8*)&wtl[(lane & 15) + 16 * nt][kk * 32 + kbase];
                acc[nt] = MFMA_BF(ah[kk], bh, acc[nt]);
                acc[nt] = MFMA_BF(ah[kk], bl, acc[nt]);
                acc[nt] = MFMA_BF(al[kk], bh, acc[nt]);
            }
        }

        if (m < 2) {
            _Float16* dst = (m == 0) ? k_ws : q_ws;
            #pragma unroll
            for (int nt = 0; nt < 4; ++nt)
                #pragma unroll
                for (int r = 0; r < 4; ++r)
                    dst[(size_t)(rrow + r) * CMID + (lane & 15) + 16 * nt] =
                        (_Float16)acc[nt][r];
        } else {
            const int b = rrow >> 12;
            const int n = rrow & (NPOS - 1);
            #pragma unroll
            for (int nt = 0; nt < 4; ++nt) {
                int cv = (lane & 15) + 16 * nt;
                union { __bf16 h[4]; uint2 u; } pk;
                #pragma unroll
                for (int r = 0; r < 4; ++r) pk.h[r] = (__bf16)acc[nt][r];
                *(uint2*)(vT_ws + ((size_t)b * CMID + cv) * NPOS + n) = pk.u;
            }
        }
    }
}

// ---------------------------------------------------------------------------
// flash_kernel: streaming attention, j-split partials (no max subtraction;
// partial sums add linearly). scores via fp16 MFMA (k,q fp16-accurate).
// Writes UNNORMALIZED partial numerators (bf16) + partial denominators (f32).
// grid (64, 8, NSPLIT): i-tile, batch, j-range split
// ---------------------------------------------------------------------------
__global__ __launch_bounds__(256) void flash_kernel(
    const _Float16* __restrict__ k_ws,  // [32768][64]
    const _Float16* __restrict__ q_ws,  // [32768][64]
    const __bf16* __restrict__ vT_ws,   // [8][64][4096]
    __bf16* __restrict__ po,            // [NSPLIT][32768][64] partial numerators
    float* __restrict__ pden)           // [NSPLIT][32768]
{
    const int b = blockIdx.y;
    const int i0 = blockIdx.x * 64;
    const int sblk = blockIdx.z;
    const int jbase = sblk * (NPOS / NSPLIT);
    const int lane = threadIdx.x & 63;
    const int wv = threadIdx.x >> 6;
    const int kb = ((lane >> 4) & 3) * 8;

    __shared__ _Float16 qt[64][72];      // q [j][c] fp16
    __shared__ __bf16 vt[64][72];        // [cv][j]
    __shared__ __bf16 pt[4][16][72];     // per-wave P tile [i][j]

    // K-tile A-fragments in registers for block lifetime
    f16x8 a0, a1;
    {
        size_t off = ((size_t)(b * NPOS + i0 + wv * 16 + (lane & 15))) * CMID + kb;
        a0 = *(const f16x8*)(k_ws + off);
        a1 = *(const f16x8*)(k_ws + off + 32);
    }

    f32x4 o[4] = {f32x4{0,0,0,0}, f32x4{0,0,0,0}, f32x4{0,0,0,0}, f32x4{0,0,0,0}};
    float den[4] = {0.f, 0.f, 0.f, 0.f};

    for (int j0 = jbase; j0 < jbase + NPOS / NSPLIT; j0 += 64) {
        {
            int r = threadIdx.x >> 2, c0 = (threadIdx.x & 3) * 16;
            const uint4* sq = (const uint4*)(q_ws + ((size_t)(b * NPOS + j0 + r)) * CMID + c0);
            uint4 h0 = sq[0], h1 = sq[1];
            *(uint4*)&qt[r][c0] = h0;
            *(uint4*)&qt[r][c0 + 8] = h1;
            const uint4* sv = (const uint4*)(vT_ws + ((size_t)b * CMID + r) * NPOS + j0 + c0);
            uint4 v0 = sv[0], v1 = sv[1];
            *(uint4*)&vt[r][c0] = v0;
            *(uint4*)&vt[r][c0 + 8] = v1;
        }
        __syncthreads();

        // S fragments: fp16 MFMA, K=64 in two chunks
        f32x4 s[4];
        #pragma unroll
        for (int nt = 0; nt < 4; ++nt) {
            f16x8 b0 = *(const f16x8*)&qt[(lane & 15) + 16 * nt][kb];
            f16x8 b1 = *(const f16x8*)&qt[(lane & 15) + 16 * nt][32 + kb];
            f32x4 z = {0.f, 0.f, 0.f, 0.f};
            z = MFMA_F16(a0, b0, z);
            z = MFMA_F16(a1, b1, z);
            s[nt] = z;
        }

        // exp; den accumulates bf16-ROUNDED p (consistent with numerator)
        #pragma unroll
        for (int nt = 0; nt < 4; ++nt) {
            #pragma unroll
            for (int r = 0; r < 4; ++r) {
                float p = __expf(s[nt][r]);
                __bf16 pb = (__bf16)p;
                den[r] += (float)pb;
                pt[wv][((lane >> 4) & 3) * 4 + r][(lane & 15) + 16 * nt] = pb;
            }
        }

        // PV accumulate (same-wave DS write->read is ordered)
        #pragma unroll
        for (int kk = 0; kk < 2; ++kk) {
            bf16_8 pa = *(const bf16_8*)&pt[wv][lane & 15][kk * 32 + kb];
            #pragma unroll
            for (int nt = 0; nt < 4; ++nt) {
                bf16_8 vb = *(const bf16_8*)&vt[(lane & 15) + 16 * nt][kk * 32 + kb];
                o[nt] = MFMA_BF(pa, vb, o[nt]);
            }
        }
        __syncthreads();
    }

    // reduce den across the 16-lane j-group
    #pragma unroll
    for (int r = 0; r < 4; ++r) {
        float d = den[r];
        d += __shfl_xor(d, 1);
        d += __shfl_xor(d, 2);
        d += __shfl_xor(d, 4);
        d += __shfl_xor(d, 8);
        den[r] = d;
    }

    const int rbase = b * NPOS + i0 + wv * 16 + ((lane >> 4) & 3) * 4;
    #pragma unroll
    for (int nt = 0; nt < 4; ++nt)
        #pragma unroll
        for (int r = 0; r < 4; ++r)
            po[((size_t)sblk * NROWS + rbase + r) * CMID + (lane & 15) + 16 * nt] =
                (__bf16)o[nt][r];
    if ((lane & 15) == 0) {
        #pragma unroll
        for (int r = 0; r < 4; ++r)
            pden[(size_t)sblk * NROWS + rbase + r] = den[r];
    }
}

// ---------------------------------------------------------------------------
// out_kernel: combine j-split partials (normalize) + attn @ Wo + BatchNorm.
// grid 2048, block 256 (thread = output channel), 16 rows per block
// ---------------------------------------------------------------------------
__global__ __launch_bounds__(256) void out_kernel(
    const __bf16* __restrict__ po,      // [NSPLIT][32768][64]
    const float* __restrict__ pden,     // [NSPLIT][32768]
    const float* __restrict__ Wo,       // [64][256]
    const float* __restrict__ gamma, const float* __restrict__ beta,
    const float* __restrict__ mmean, const float* __restrict__ mvar,
    float* __restrict__ out)            // [32768][256]
{
    const int r0 = blockIdx.x * 16;
    const int t = threadIdx.x;

    __shared__ float at[16][64];
    __shared__ float dinv[16];

    if (t < 16) {
        float d = 0.f;
        #pragma unroll
        for (int s = 0; s < NSPLIT; ++s) d += pden[(size_t)s * NROWS + r0 + t];
        dinv[t] = 1.0f / d;
    }
    __syncthreads();

    for (int idx = t; idx < 16 * 64; idx += 256) {
        int r = idx >> 6, c = idx & 63;
        float sum = 0.f;
        #pragma unroll
        for (int s = 0; s < NSPLIT; ++s)
            sum += (float)po[((size_t)s * NROWS + r0 + r) * CMID + c];
        at[r][c] = sum * dinv[r];
    }
    __syncthreads();

    float acc[16];
    #pragma unroll
    for (int r = 0; r < 16; ++r) acc[r] = 0.f;

    for (int k = 0; k < 64; ++k) {
        float w = Wo[k * OC + t];
        #pragma unroll
        for (int r = 0; r < 16; ++r) acc[r] += at[r][k] * w;
    }

    const float sc = gamma[t] * rsqrtf(mvar[t] + 1e-3f);
    const float sh = beta[t] - mmean[t] * sc;
    #pragma unroll
    for (int r = 0; r < 16; ++r)
        out[(size_t)(r0 + r) * OC + t] = acc[r] * sc + sh;
}

// ---------------------------------------------------------------------------
extern "C" void kernel_launch(void* const* d_in, const int* in_sizes, int n_in,
                              void* d_out, int out_size, void* d_ws, size_t ws_size,
                              hipStream_t stream) {
    const float* x     = (const float*)d_in[0];
    const float* Wk    = (const float*)d_in[1];
    const float* Wq    = (const float*)d_in[2];
    const float* Wv    = (const float*)d_in[3];
    const float* Wo    = (const float*)d_in[4];
    const float* gamma = (const float*)d_in[5];
    const float* beta  = (const float*)d_in[6];
    const float* mmean = (const float*)d_in[7];
    const float* mvar  = (const float*)d_in[8];
    float* out = (float*)d_out;

    char* base = (char*)d_ws;
    const size_t MB4 = (size_t)NROWS * CMID * 2;        // 4 MiB
    _Float16* k_ws = (_Float16*)base;                   // 4 MiB
    _Float16* q_ws = (_Float16*)(base + MB4);           // 4 MiB
    __bf16*   vT   = (__bf16*)(base + 2 * MB4);         // 4 MiB
    __bf16*   po   = (__bf16*)(base + 3 * MB4);         // NSPLIT*4 MiB = 8 MiB
    float*    pden = (float*)(base + (3 + NSPLIT) * MB4); // 256 KiB
    // total: 20.25 MiB

    proj_kernel<<<512, 256, 0, stream>>>(x, Wk, Wq, Wv, k_ws, q_ws, vT);
    flash_kernel<<<dim3(64, 8, NSPLIT), 256, 0, stream>>>(k_ws, q_ws, vT, po, pden);
    out_kernel<<<2048, 256, 0, stream>>>(po, pden, Wo, gamma, beta, mmean, mvar, out);
}

// Round 5
// 114.748 us; speedup vs baseline: 1.6501x; 1.1126x over previous
//
#include <hip/hip_runtime.h>
#include <hip/hip_bf16.h>

typedef __bf16 bf16_8 __attribute__((ext_vector_type(8)));
typedef _Float16 f16x8 __attribute__((ext_vector_type(8)));
typedef float f32x4 __attribute__((ext_vector_type(4)));
typedef float f32x16 __attribute__((ext_vector_type(16)));

#define MFMA_BF(A, B, C) __builtin_amdgcn_mfma_f32_16x16x32_bf16(A, B, C, 0, 0, 0)
#define MFMA32_F16(A, B, C) __builtin_amdgcn_mfma_f32_32x32x16_f16(A, B, C, 0, 0, 0)
#define MFMA32_BF(A, B, C) __builtin_amdgcn_mfma_f32_32x32x16_bf16(A, B, C, 0, 0, 0)

#define BATCH 8
#define NPOS 4096            // 64*64 spatial
#define CIN 256
#define CMID 64
#define OC 256
#define NROWS (BATCH * NPOS) // 32768
#define NSPLIT 4             // j-range split for flash parallelism

// lane i <-> lane i+32 register swap (hi half of a <-> lo half of b)
__device__ inline void swaplane32(unsigned& a, unsigned& b) {
    asm volatile("v_permlane32_swap_b32 %0, %1" : "+v"(a), "+v"(b));
}

// ---------------------------------------------------------------------------
// proj_kernel (fused): k,q,v = x @ {Wk,Wq,Wv}. x read ONCE into registers
// (bf16 hi/lo pairs), W staged hi/lo in LDS. Split-precision 3-term MFMA
// gives fp32-accurate results (~1e-4). k,q stored fp16; v stored bf16
// transposed vT[b][cv][n]. grid 512, block 256.
// ---------------------------------------------------------------------------
__global__ __launch_bounds__(256) void proj_kernel(
    const float* __restrict__ x,
    const float* __restrict__ Wk, const float* __restrict__ Wq,
    const float* __restrict__ Wv,
    _Float16* __restrict__ k_ws, _Float16* __restrict__ q_ws,
    __bf16* __restrict__ vT_ws)
{
    const int r0 = blockIdx.x * 64;

    __shared__ __bf16 wth[64][264];
    __shared__ __bf16 wtl[64][264];

    const int lane = threadIdx.x & 63;
    const int wv = threadIdx.x >> 6;
    const int kbase = ((lane >> 4) & 3) * 8;
    const int arow = r0 + wv * 16 + (lane & 15);
    const float* xrow = x + (size_t)arow * CIN;

    // x tile -> registers, split hi/lo
    bf16_8 ah[8], al[8];
    #pragma unroll
    for (int kk = 0; kk < 8; ++kk) {
        const float4* xp = (const float4*)(xrow + kk * 32 + kbase);
        float4 x0 = xp[0], x1 = xp[1];
        float xs[8] = {x0.x, x0.y, x0.z, x0.w, x1.x, x1.y, x1.z, x1.w};
        #pragma unroll
        for (int e = 0; e < 8; ++e) {
            __bf16 h = (__bf16)xs[e];
            ah[kk][e] = h;
            al[kk][e] = (__bf16)(xs[e] - (float)h);
        }
    }

    const float* Ws[3] = {Wk, Wq, Wv};
    const int rrow = r0 + wv * 16 + ((lane >> 4) & 3) * 4;

    for (int m = 0; m < 3; ++m) {
        __syncthreads();   // previous iteration's LDS reads complete
        for (int idx = threadIdx.x; idx < 64 * 256; idx += 256) {
            int col = idx & 63, k = idx >> 6;
            float f = Ws[m][k * 64 + col];
            __bf16 h = (__bf16)f;
            wth[col][k] = h;
            wtl[col][k] = (__bf16)(f - (float)h);
        }
        __syncthreads();

        f32x4 acc[4] = {f32x4{0,0,0,0}, f32x4{0,0,0,0}, f32x4{0,0,0,0}, f32x4{0,0,0,0}};
        #pragma unroll
        for (int kk = 0; kk < 8; ++kk) {
            #pragma unroll
            for (int nt = 0; nt < 4; ++nt) {
                bf16_8 bh = *(const bf16_8*)&wth[(lane & 15) + 16 * nt][kk * 32 + kbase];
                bf16_8 bl = *(const bf16_8*)&wtl[(lane & 15) + 16 * nt][kk * 32 + kbase];
                acc[nt] = MFMA_BF(ah[kk], bh, acc[nt]);
                acc[nt] = MFMA_BF(ah[kk], bl, acc[nt]);
                acc[nt] = MFMA_BF(al[kk], bh, acc[nt]);
            }
        }

        if (m < 2) {
            _Float16* dst = (m == 0) ? k_ws : q_ws;
            #pragma unroll
            for (int nt = 0; nt < 4; ++nt)
                #pragma unroll
                for (int r = 0; r < 4; ++r)
                    dst[(size_t)(rrow + r) * CMID + (lane & 15) + 16 * nt] =
                        (_Float16)acc[nt][r];
        } else {
            const int b = rrow >> 12;
            const int n = rrow & (NPOS - 1);
            #pragma unroll
            for (int nt = 0; nt < 4; ++nt) {
                int cv = (lane & 15) + 16 * nt;
                union { __bf16 h[4]; uint2 u; } pk;
                #pragma unroll
                for (int r = 0; r < 4; ++r) pk.h[r] = (__bf16)acc[nt][r];
                *(uint2*)(vT_ws + ((size_t)b * CMID + cv) * NPOS + n) = pk.u;
            }
        }
    }
}

// ---------------------------------------------------------------------------
// flash_kernel: streaming attention, 32x32 swapped-QK^T, in-register P.
//   S^T = mfma32(A=q, B=k): lane owns i = lane&31 (lane, lane+32 share i,
//   complementary j halves). exp in-register; bf16-pack + permlane32_swap
//   builds PV A-fragments with NO LDS P round-trip.
// Writes UNNORMALIZED partial numerators (bf16) + partial denominators (f32).
// grid (32, 8, NSPLIT): 128-row i-tile, batch, j-range split. 4 waves/block.
// ---------------------------------------------------------------------------
__global__ __launch_bounds__(256, 4) void flash_kernel(
    const _Float16* __restrict__ k_ws,  // [32768][64]
    const _Float16* __restrict__ q_ws,  // [32768][64]
    const __bf16* __restrict__ vT_ws,   // [8][64][4096]
    __bf16* __restrict__ po,            // [NSPLIT][32768][64] partial numerators
    float* __restrict__ pden)           // [NSPLIT][32768]
{
    const int b = blockIdx.y;
    const int i0 = blockIdx.x * 128;
    const int sblk = blockIdx.z;
    const int jbase = sblk * (NPOS / NSPLIT);
    const int lane = threadIdx.x & 63;
    const int wv = threadIdx.x >> 6;
    const int l31 = lane & 31;
    const int g = lane >> 5;            // half-wave index

    __shared__ _Float16 qt[64][72];     // q [j][c] fp16
    __shared__ __bf16 vt[64][72];       // [cv][j] bf16

    // wave's 32 k-rows as B-fragments (col = l31, k-elems = g*8+e per chunk)
    f16x8 kf[4];
    {
        const _Float16* kp =
            k_ws + ((size_t)(b * NPOS + i0 + wv * 32 + l31)) * CMID + g * 8;
        #pragma unroll
        for (int c = 0; c < 4; ++c) kf[c] = *(const f16x8*)(kp + c * 16);
    }

    f32x16 o0 = {0,0,0,0,0,0,0,0,0,0,0,0,0,0,0,0};
    f32x16 o1 = {0,0,0,0,0,0,0,0,0,0,0,0,0,0,0,0};
    float den = 0.f;

    for (int j0 = jbase; j0 < jbase + NPOS / NSPLIT; j0 += 64) {
        {   // stage q (fp16) and vT (bf16) tiles: 32B per thread each
            int r = threadIdx.x >> 2, c0 = (threadIdx.x & 3) * 16;
            const uint4* sq = (const uint4*)(q_ws + ((size_t)(b * NPOS + j0 + r)) * CMID + c0);
            uint4 h0 = sq[0], h1 = sq[1];
            *(uint4*)&qt[r][c0] = h0;
            *(uint4*)&qt[r][c0 + 8] = h1;
            const uint4* sv = (const uint4*)(vT_ws + ((size_t)b * CMID + r) * NPOS + j0 + c0);
            uint4 v0 = sv[0], v1 = sv[1];
            *(uint4*)&vt[r][c0] = v0;
            *(uint4*)&vt[r][c0 + 8] = v1;
        }
        __syncthreads();

        #pragma unroll
        for (int jj = 0; jj < 2; ++jj) {
            // S^T: A = q rows (lane row = l31), B = k (lane col = l31 = i)
            f16x8 aq[4];
            #pragma unroll
            for (int c = 0; c < 4; ++c)
                aq[c] = *(const f16x8*)&qt[jj * 32 + l31][c * 16 + g * 8];
            f32x16 s = {0,0,0,0,0,0,0,0,0,0,0,0,0,0,0,0};
            #pragma unroll
            for (int c = 0; c < 4; ++c) s = MFMA32_F16(aq[c], kf[c], s);
            // lane's S regs: j_local = (reg&3) + 8*(reg>>2) + 4*g, i = l31

            // exp (bf16-rounded, den-consistent) + pack pairs into words
            unsigned pk[8];
            #pragma unroll
            for (int m = 0; m < 8; ++m) {
                __bf16 b0 = (__bf16)__expf(s[2 * m]);
                __bf16 b1 = (__bf16)__expf(s[2 * m + 1]);
                den += (float)b0 + (float)b1;
                union { __bf16 h[2]; unsigned u; } w;
                w.h[0] = b0; w.h[1] = b1;
                pk[m] = w.u;
            }
            // cross-half exchange: after swaps, frag words are uniform:
            // chunk0 (j 0..15): {pk0,pk1,pk2,pk3}; chunk1: {pk4,pk5,pk6,pk7}
            swaplane32(pk[0], pk[2]);
            swaplane32(pk[1], pk[3]);
            swaplane32(pk[4], pk[6]);
            swaplane32(pk[5], pk[7]);
            union { unsigned u[4]; bf16_8 v; } pa0, pa1;
            pa0.u[0] = pk[0]; pa0.u[1] = pk[1]; pa0.u[2] = pk[2]; pa0.u[3] = pk[3];
            pa1.u[0] = pk[4]; pa1.u[1] = pk[5]; pa1.u[2] = pk[6]; pa1.u[3] = pk[7];

            // PV: A = P (lane row = l31 = i), B = V (lane col = cv)
            {
                bf16_8 bv0 = *(const bf16_8*)&vt[l31][jj * 32 + g * 8];
                bf16_8 bv1 = *(const bf16_8*)&vt[l31][jj * 32 + 16 + g * 8];
                o0 = MFMA32_BF(pa0.v, bv0, o0);
                o0 = MFMA32_BF(pa1.v, bv1, o0);
            }
            {
                bf16_8 bv0 = *(const bf16_8*)&vt[32 + l31][jj * 32 + g * 8];
                bf16_8 bv1 = *(const bf16_8*)&vt[32 + l31][jj * 32 + 16 + g * 8];
                o1 = MFMA32_BF(pa0.v, bv0, o1);
                o1 = MFMA32_BF(pa1.v, bv1, o1);
            }
        }
        __syncthreads();
    }

    // full denominator for i = l31 (other j-half lives in partner lane)
    den += __shfl_xor(den, 32);

    const size_t rowb = (size_t)b * NPOS + i0 + wv * 32;
    if (lane < 32)
        pden[(size_t)sblk * NROWS + rowb + lane] = den;

    // O layout: col = cv = l31 (+32 for o1), row_local = (reg&3)+8*(reg>>2)+4g
    #pragma unroll
    for (int reg = 0; reg < 16; ++reg) {
        int il = (reg & 3) + 8 * (reg >> 2) + 4 * g;
        size_t base = ((size_t)sblk * NROWS + rowb + il) * CMID + l31;
        po[base]      = (__bf16)o0[reg];
        po[base + 32] = (__bf16)o1[reg];
    }
}

// ---------------------------------------------------------------------------
// out_kernel: combine j-split partials (normalize) + attn @ Wo + BatchNorm.
// grid 2048, block 256 (thread = output channel), 16 rows per block
// ---------------------------------------------------------------------------
__global__ __launch_bounds__(256) void out_kernel(
    const __bf16* __restrict__ po,      // [NSPLIT][32768][64]
    const float* __restrict__ pden,     // [NSPLIT][32768]
    const float* __restrict__ Wo,       // [64][256]
    const float* __restrict__ gamma, const float* __restrict__ beta,
    const float* __restrict__ mmean, const float* __restrict__ mvar,
    float* __restrict__ out)            // [32768][256]
{
    const int r0 = blockIdx.x * 16;
    const int t = threadIdx.x;

    __shared__ float at[16][64];
    __shared__ float dinv[16];

    if (t < 16) {
        float d = 0.f;
        #pragma unroll
        for (int s = 0; s < NSPLIT; ++s) d += pden[(size_t)s * NROWS + r0 + t];
        dinv[t] = 1.0f / d;
    }
    __syncthreads();

    for (int idx = t; idx < 16 * 64; idx += 256) {
        int r = idx >> 6, c = idx & 63;
        float sum = 0.f;
        #pragma unroll
        for (int s = 0; s < NSPLIT; ++s)
            sum += (float)po[((size_t)s * NROWS + r0 + r) * CMID + c];
        at[r][c] = sum * dinv[r];
    }
    __syncthreads();

    float acc[16];
    #pragma unroll
    for (int r = 0; r < 16; ++r) acc[r] = 0.f;

    for (int k = 0; k < 64; ++k) {
        float w = Wo[k * OC + t];
        #pragma unroll
        for (int r = 0; r < 16; ++r) acc[r] += at[r][k] * w;
    }

    const float sc = gamma[t] * rsqrtf(mvar[t] + 1e-3f);
    const float sh = beta[t] - mmean[t] * sc;
    #pragma unroll
    for (int r = 0; r < 16; ++r)
        out[(size_t)(r0 + r) * OC + t] = acc[r] * sc + sh;
}

// ---------------------------------------------------------------------------
extern "C" void kernel_launch(void* const* d_in, const int* in_sizes, int n_in,
                              void* d_out, int out_size, void* d_ws, size_t ws_size,
                              hipStream_t stream) {
    const float* x     = (const float*)d_in[0];
    const float* Wk    = (const float*)d_in[1];
    const float* Wq    = (const float*)d_in[2];
    const float* Wv    = (const float*)d_in[3];
    const float* Wo    = (const float*)d_in[4];
    const float* gamma = (const float*)d_in[5];
    const float* beta  = (const float*)d_in[6];
    const float* mmean = (const float*)d_in[7];
    const float* mvar  = (const float*)d_in[8];
    float* out = (float*)d_out;

    // k/q/vT live in d_out (33.5 MB): only read by flash_kernel, which
    // completes before out_kernel overwrites d_out. po/pden in d_ws.
    char* ob = (char*)d_out;
    const size_t MB4 = (size_t)NROWS * CMID * 2;   // 4 MiB
    _Float16* k_ws = (_Float16*)ob;                // 4 MiB
    _Float16* q_ws = (_Float16*)(ob + MB4);        // 4 MiB
    __bf16*   vT   = (__bf16*)(ob + 2 * MB4);      // 4 MiB

    __bf16* po   = (__bf16*)d_ws;                              // 16 MiB
    float*  pden = (float*)((char*)d_ws + (size_t)NSPLIT * MB4); // 512 KiB

    proj_kernel<<<512, 256, 0, stream>>>(x, Wk, Wq, Wv, k_ws, q_ws, vT);
    flash_kernel<<<dim3(32, 8, NSPLIT), 256, 0, stream>>>(k_ws, q_ws, vT, po, pden);
    out_kernel<<<2048, 256, 0, stream>>>(po, pden, Wo, gamma, beta, mmean, mvar, out);
}